// Round 8
// baseline (147.630 us; speedup 1.0000x reference)
//
#include <hip/hip_runtime.h>
#include <math.h>
#include <stdint.h>

#define CDIM 128
#define NTOT 4096

typedef _Float16 f16x8 __attribute__((ext_vector_type(8)));  // 8 fp16 (4 VGPRs)
typedef float floatx4 __attribute__((ext_vector_type(4)));   // MFMA accumulator

static __device__ __forceinline__ floatx4 mfma16(f16x8 a, f16x8 b, floatx4 c) {
    return __builtin_amdgcn_mfma_f32_16x16x32_f16(a, b, c, 0, 0, 0);
}
static __device__ __forceinline__ unsigned short f2h(float f) {
    _Float16 h = (_Float16)f;
    return __builtin_bit_cast(unsigned short, h);
}
static __device__ __forceinline__ float h2f(unsigned short u) {
    return (float)__builtin_bit_cast(_Float16, u);
}

// XOR-swizzled LDS addressing, rows of 128 ush (16 chunks of 16 B):
// chunk cc stored at linear slot cc ^ (row & 15).
#define SWZ(row, cc) ((((row) << 7)) + ((((cc) ^ ((row) & 15))) << 3))
// rows of 64 ush (8 chunks of 16 B): chunk cc at slot cc ^ (row & 7).
#define SWZ8(row, cc) ((((row) << 6)) + ((((cc) ^ ((row) & 7))) << 3))

// async global->LDS, 16 B per lane. LDS dest = wave-uniform base + lane*16
// (linear); swizzle realized by inverse-permuting the per-lane GLOBAL source.
static __device__ __forceinline__ void gload_lds16(const void* g, void* l) {
    __builtin_amdgcn_global_load_lds(
        (const __attribute__((address_space(1))) void*)g,
        (__attribute__((address_space(3))) void*)l, 16, 0, 0);
}

// ---------------------------------------------------------------------------
// One-shot fp32 -> fp16 conversion of the 4 weight matrices (128x128 each).
// Wh layout: [4][16384] fp16 = {Wq, Wk, Wv, Wo}. grid (16, 4), 256 thr.
// ---------------------------------------------------------------------------
__global__ __launch_bounds__(256) void wcvt_kernel(
    const float* __restrict__ Wq, const float* __restrict__ Wk,
    const float* __restrict__ Wv, const float* __restrict__ Wo,
    unsigned short* __restrict__ Wh)
{
    const float* src = (blockIdx.y == 0) ? Wq : (blockIdx.y == 1) ? Wk
                     : (blockIdx.y == 2) ? Wv : Wo;
    const int i = (blockIdx.x * 256 + threadIdx.x) * 4;
    float4 f = *(const float4*)&src[i];
    ushort4 u = { f2h(f.x), f2h(f.y), f2h(f.z), f2h(f.w) };
    *(ushort4*)&Wh[(size_t)blockIdx.y * 16384 + i] = u;
}

// ---------------------------------------------------------------------------
// Fused q/k/v projection. v8: MAX-OCCUPANCY form. 128-thr blocks (2 waves),
// n-tile 16, LDS = 4.3 KB (X tile only) -> wave-slot-limited occupancy
// (16 blocks = 32 waves/CU, 4x prior TLP). W fragments direct from global
// fp16 (L1/L2 broadcast; R2/R3 showed this is neutral vs LDS-staged W).
// Waves split o: wave w owns o in [w*64, w*64+64). grid 1024 flat,
// XCD-swizzled. Outputs fp16: qo, ko: [b][n][c]; vo: [b][c][n].
// ---------------------------------------------------------------------------
__global__ __launch_bounds__(128) void qkv_proj_kernel(
    const float* __restrict__ x, const unsigned short* __restrict__ Wh,
    const float* __restrict__ bq, const float* __restrict__ bk,
    const float* __restrict__ bv,
    unsigned short* __restrict__ qo, unsigned short* __restrict__ ko,
    unsigned short* __restrict__ vo)
{
    __shared__ __align__(16) unsigned short Xs[16][136];   // [n][c] fp16

    const int t = threadIdx.x;
    const int bid = blockIdx.x;                       // 1024
    const int swz = ((bid & 7) << 7) | (bid >> 3);    // bijective, 128/XCD chunks
    const int b = swz >> 8;
    const int n0 = (swz & 255) * 16;
    const int w = t >> 6, quad = (t >> 4) & 3, l15 = t & 15;

    // stage x tile 16n x 128c with transpose-on-store: thread covers 4n x 4c
    {
        const int n = (t & 3) * 4;
        const int c = (t >> 2) * 4;
        float4 xr[4];
        #pragma unroll
        for (int j = 0; j < 4; ++j)
            xr[j] = *(const float4*)&x[((size_t)b * CDIM + c + j) * NTOT + n0 + n];
        #pragma unroll
        for (int k = 0; k < 4; ++k) {
            ushort4 u;
            u.x = f2h(((const float*)&xr[0])[k]);
            u.y = f2h(((const float*)&xr[1])[k]);
            u.z = f2h(((const float*)&xr[2])[k]);
            u.w = f2h(((const float*)&xr[3])[k]);
            *(ushort4*)&Xs[n + k][c] = u;
        }
    }
    __syncthreads();

    f16x8 xf[4];
    #pragma unroll
    for (int f = 0; f < 4; ++f)
        xf[f] = *(const f16x8*)&Xs[l15][f * 32 + quad * 8];

    // q, k: C[o][n], A = W, B = X. Wave w owns o-half w*64 (4 ot).
    #pragma unroll
    for (int s = 0; s < 2; ++s) {
        const unsigned short* Wm = Wh + (size_t)s * 16384;
        const float* bias = s ? bk : bq;
        unsigned short* dst = s ? ko : qo;
        #pragma unroll
        for (int ot = 0; ot < 4; ++ot) {
            const int o = w * 64 + ot * 16;
            floatx4 acc = (floatx4){0.f, 0.f, 0.f, 0.f};
            #pragma unroll
            for (int f = 0; f < 4; ++f) {
                f16x8 aW = *(const f16x8*)
                    &Wm[(size_t)(o + l15) * CDIM + f * 32 + quad * 8];
                acc = mfma16(aW, xf[f], acc);
            }
            const int ob = o + quad * 4;
            ushort4 u;
            u.x = f2h(acc[0] + bias[ob + 0]);
            u.y = f2h(acc[1] + bias[ob + 1]);
            u.z = f2h(acc[2] + bias[ob + 2]);
            u.w = f2h(acc[3] + bias[ob + 3]);
            *(ushort4*)&dst[((size_t)b * NTOT + n0 + l15) * CDIM + ob] = u;
        }
    }
    // v: C'[n][o], A = X, B = W
    {
        const unsigned short* Wm = Wh + 2 * 16384;
        #pragma unroll
        for (int ot = 0; ot < 4; ++ot) {
            const int o = w * 64 + ot * 16 + l15;
            floatx4 acc = (floatx4){0.f, 0.f, 0.f, 0.f};
            #pragma unroll
            for (int f = 0; f < 4; ++f) {
                f16x8 bW = *(const f16x8*)
                    &Wm[(size_t)o * CDIM + f * 32 + quad * 8];
                acc = mfma16(xf[f], bW, acc);
            }
            const float bv_ = bv[o];
            ushort4 u;
            u.x = f2h(acc[0] + bv_); u.y = f2h(acc[1] + bv_);
            u.z = f2h(acc[2] + bv_); u.w = f2h(acc[3] + bv_);
            *(ushort4*)&vo[((size_t)b * CDIM + o) * NTOT + n0 + quad * 4] = u;
        }
    }
}

// ---------------------------------------------------------------------------
// Flash attention, split-K(4). v6 (UNCHANGED from R5/R7): software-pipelined
// softmax -- per iter QK[i] and PV[i-1] issue back-to-back on the MFMA pipe
// while softmax[i] runs on the VALU pipe.
// ---------------------------------------------------------------------------
__global__ __launch_bounds__(256, 2) void attn_kernel(
    const unsigned short* __restrict__ qg,
    const unsigned short* __restrict__ kg,
    const unsigned short* __restrict__ vg,
    unsigned short* __restrict__ Op,
    float* __restrict__ Ms, float* __restrict__ Ls)
{
    __shared__ __align__(16) unsigned short Kb[2][64 * 128];  // 32 KB
    __shared__ __align__(16) unsigned short Vb[2][128 * 64];  // 32 KB
    __shared__ __align__(16) unsigned short Ps[128 * 64];     // 16 KB wave-private rows

    const int t = threadIdx.x;
    const int w = t >> 6, quad = (t >> 4) & 3, l15 = t & 15;

    const int bid = blockIdx.x;
    const int swz = ((bid & 7) << 6) | (bid >> 3);
    const int gidx = swz >> 5;            // 0..15 = (b,z) group
    const int b = gidx & 3;
    const int z = gidx >> 2;
    const int i0 = (swz & 31) * 128;
    const int jbase = z * 1024;
    const size_t vbase = (size_t)b * CDIM * NTOT;

    // Q B-fragments direct from global
    f16x8 bQ[2][4];
    #pragma unroll
    for (int nt = 0; nt < 2; ++nt) {
        const size_t qrow = ((size_t)b * NTOT + i0 + w * 32 + nt * 16 + l15) * CDIM;
        #pragma unroll
        for (int f = 0; f < 4; ++f)
            bQ[nt][f] = *(const f16x8*)&qg[qrow + f * 32 + quad * 8];
    }

    auto stageK = [&](unsigned short* Kd, int j0) {
        const size_t kbase = ((size_t)b * NTOT + j0) * CDIM;
        #pragma unroll
        for (int r = 0; r < 4; ++r) {
            const int flat = r * 256 + t;
            const int ldsoff = (r * 256 + (t & ~63)) * 8;  // wave-uniform, ush
            const int krow = flat >> 4, kcc = flat & 15;
            gload_lds16(&kg[kbase + (size_t)krow * CDIM + ((kcc ^ (krow & 15)) << 3)],
                        &Kd[ldsoff]);
        }
    };
    auto stageV = [&](unsigned short* Vd, int j0) {
        const size_t vrow0 = vbase + j0;
        #pragma unroll
        for (int r = 0; r < 4; ++r) {
            const int flat = r * 256 + t;
            const int ldsoff = (r * 256 + (t & ~63)) * 8;
            const int vrow = flat >> 3, vcc = flat & 7;
            gload_lds16(&vg[vrow0 + (size_t)vrow * NTOT + ((vcc ^ (vrow & 7)) << 3)],
                        &Vd[ldsoff]);
        }
    };

    floatx4 accO[2][8];   // [nt][dt]
    #pragma unroll
    for (int nt = 0; nt < 2; ++nt)
        #pragma unroll
        for (int dt = 0; dt < 8; ++dt) accO[nt][dt] = (floatx4){0.f, 0.f, 0.f, 0.f};
    float m_run[2] = {-INFINITY, -INFINITY};
    float l_part[2] = {0.f, 0.f};

    floatx4 accT[2][4];
    uint2 pu[2][4];
    f16x8 bP[2][2];

    auto QK = [&](const unsigned short* Kd) {
        #pragma unroll
        for (int nt = 0; nt < 2; ++nt)
            #pragma unroll
            for (int jt = 0; jt < 4; ++jt) accT[nt][jt] = (floatx4){0.f, 0.f, 0.f, 0.f};
        __builtin_amdgcn_s_setprio(1);
        #pragma unroll
        for (int jt = 0; jt < 4; ++jt)
            #pragma unroll
            for (int f = 0; f < 4; ++f) {
                f16x8 aK = *(const f16x8*)&Kd[SWZ(jt * 16 + l15, f * 4 + quad)];
                accT[0][jt] = mfma16(aK, bQ[0][f], accT[0][jt]);
                accT[1][jt] = mfma16(aK, bQ[1][f], accT[1][jt]);
            }
        __builtin_amdgcn_s_setprio(0);
    };
    auto RB = [&]() {   // read P[i-1] fragments (own rows) early
        #pragma unroll
        for (int nt = 0; nt < 2; ++nt) {
            const int prow = w * 32 + nt * 16 + l15;
            #pragma unroll
            for (int kb = 0; kb < 2; ++kb)
                bP[nt][kb] = *(const f16x8*)&Ps[SWZ8(prow, kb * 4 + quad)];
        }
    };
    auto PV = [&](const unsigned short* Vd) {
        __builtin_amdgcn_s_setprio(1);
        #pragma unroll
        for (int dt = 0; dt < 8; ++dt)
            #pragma unroll
            for (int kb = 0; kb < 2; ++kb) {
                f16x8 aV = *(const f16x8*)&Vd[SWZ8(dt * 16 + l15, kb * 4 + quad)];
                accO[0][dt] = mfma16(aV, bP[0][kb], accO[0][dt]);
                accO[1][dt] = mfma16(aV, bP[1][kb], accO[1][dt]);
            }
        __builtin_amdgcn_s_setprio(0);
    };
    auto SM = [&]() {   // online softmax, defer-max (THR=8), pkrtz packing
        #pragma unroll
        for (int nt = 0; nt < 2; ++nt) {
            float tm = accT[nt][0][0];
            #pragma unroll
            for (int jt = 0; jt < 4; ++jt)
                #pragma unroll
                for (int r = 0; r < 4; ++r) tm = fmaxf(tm, accT[nt][jt][r]);
            tm = fmaxf(tm, __shfl_xor(tm, 16));
            tm = fmaxf(tm, __shfl_xor(tm, 32));
            if (__ballot(tm > m_run[nt] + 8.f)) {
                const float m_new = fmaxf(m_run[nt], tm);
                const float alpha = __expf(m_run[nt] - m_new);   // 0 on first tile
                m_run[nt] = m_new;
                l_part[nt] *= alpha;
                #pragma unroll
                for (int dt = 0; dt < 8; ++dt) {
                    accO[nt][dt][0] *= alpha; accO[nt][dt][1] *= alpha;
                    accO[nt][dt][2] *= alpha; accO[nt][dt][3] *= alpha;
                }
            }
            const float mcur = m_run[nt];
            float ps = 0.f;
            #pragma unroll
            for (int jt = 0; jt < 4; ++jt) {
                float p0 = __expf(accT[nt][jt][0] - mcur);
                float p1 = __expf(accT[nt][jt][1] - mcur);
                float p2 = __expf(accT[nt][jt][2] - mcur);
                float p3 = __expf(accT[nt][jt][3] - mcur);
                ps += (p0 + p1) + (p2 + p3);
                pu[nt][jt].x = __builtin_bit_cast(unsigned int,
                                   __builtin_amdgcn_cvt_pkrtz(p0, p1));
                pu[nt][jt].y = __builtin_bit_cast(unsigned int,
                                   __builtin_amdgcn_cvt_pkrtz(p2, p3));
            }
            l_part[nt] += ps;
        }
    };
    auto WP = [&]() {   // write P[i] to own rows
        #pragma unroll
        for (int nt = 0; nt < 2; ++nt) {
            const int prow = w * 32 + nt * 16 + l15;
            #pragma unroll
            for (int jt = 0; jt < 4; ++jt)
                *(uint2*)&Ps[SWZ8(prow, 2 * jt + (quad >> 1)) + (quad & 1) * 4] =
                    pu[nt][jt];
        }
    };

    stageK(Kb[0], jbase);
    stageV(Vb[0], jbase);
    unsigned short *Kc = Kb[0], *Kn = Kb[1], *Vc = Vb[0], *Vn = Vb[1];

    // ---- iter 0 (peeled): no PV, both stages early (Vb[1] virgin) ----
    asm volatile("s_waitcnt vmcnt(0) lgkmcnt(0)" ::: "memory");
    __builtin_amdgcn_s_barrier();
    stageK(Kn, jbase + 64);
    stageV(Vn, jbase + 64);
    QK(Kc);
    SM();
    WP();
    { unsigned short* tp = Kc; Kc = Kn; Kn = tp; tp = Vc; Vc = Vn; Vn = tp; }

    // ---- iters 1..14 ----
    for (int it = 1; it <= 14; ++it) {
        // (A) own K[it] landed (vmcnt(4): V[it] may still fly) + own LDS reads
        // done; barrier extends to all waves.
        asm volatile("s_waitcnt vmcnt(4) lgkmcnt(0)" ::: "memory");
        __builtin_amdgcn_s_barrier();
        RB();                                   // P[it-1] (own rows)
        stageK(Kn, jbase + (it + 1) * 64);      // K[it+1], in flight a full iter
        QK(Kc);                                 // MFMA: K[it] x Q
        PV(Vn);                                 // MFMA: V[it-1] x P[it-1]  (overlaps SM)
        SM();                                   // VALU: softmax[it]
        // (B) all waves' V[it-1] reads done -> staging V[it+1] into Vn safe.
        // K[it+1] stays in flight (no vmcnt).
        asm volatile("s_waitcnt lgkmcnt(0)" ::: "memory");
        __builtin_amdgcn_s_barrier();
        stageV(Vn, jbase + (it + 1) * 64);
        WP();                                   // P[it] (own rows)
        { unsigned short* tp = Kc; Kc = Kn; Kn = tp; tp = Vc; Vc = Vn; Vn = tp; }
    }

    // ---- iter 15 (peeled): no staging ----
    asm volatile("s_waitcnt vmcnt(4) lgkmcnt(0)" ::: "memory");
    __builtin_amdgcn_s_barrier();
    RB();
    QK(Kc);
    PV(Vn);
    SM();
    WP();
    // epilogue: all waves' V[15] staging landed before PV[15]
    asm volatile("s_waitcnt vmcnt(0)" ::: "memory");
    __builtin_amdgcn_s_barrier();
    RB();
    PV(Vc);

    // final l over quads; store normalized partials + stats
    #pragma unroll
    for (int nt = 0; nt < 2; ++nt) {
        float lf = l_part[nt];
        lf += __shfl_xor(lf, 16);
        lf += __shfl_xor(lf, 32);
        const float inv = 1.0f / lf;
        const size_t orow =
            (((size_t)z * 4 + b) * NTOT + i0 + w * 32 + nt * 16 + l15) * CDIM;
        #pragma unroll
        for (int dt = 0; dt < 8; ++dt) {
            ushort4 u;
            u.x = f2h(accO[nt][dt][0] * inv); u.y = f2h(accO[nt][dt][1] * inv);
            u.z = f2h(accO[nt][dt][2] * inv); u.w = f2h(accO[nt][dt][3] * inv);
            *(ushort4*)&Op[orow + dt * 16 + quad * 4] = u;
        }
        if (quad == 0) {
            const int idx = (z * 4 + b) * NTOT + i0 + w * 32 + nt * 16 + l15;
            Ms[idx] = m_run[nt];
            Ls[idx] = lf;
        }
    }
}

// ---------------------------------------------------------------------------
// Output projection + residual with FUSED split-K combine. v8: MAX-OCCUPANCY
// form. 128-thr blocks (2 waves), n-tile 16, LDS 4.3 KB (merged tile only),
// Wo direct from global fp16. Waves split o. grid 1024 flat, XCD-swizzled.
// ---------------------------------------------------------------------------
__global__ __launch_bounds__(128) void out_proj_kernel(
    const unsigned short* __restrict__ Op,
    const float* __restrict__ Ms, const float* __restrict__ Ls,
    const unsigned short* __restrict__ Woh, const float* __restrict__ bo,
    const float* __restrict__ x, float* __restrict__ out)
{
    __shared__ __align__(16) unsigned short As[16][136];  // [n][c] merged

    const int t = threadIdx.x;
    const int bid = blockIdx.x;                       // 1024
    const int swz = ((bid & 7) << 7) | (bid >> 3);    // bijective
    const int b = swz >> 8;
    const int n0 = (swz & 255) * 16;
    const int w = t >> 6, quad = (t >> 4) & 3, l15 = t & 15;

    const size_t PER = (size_t)NTOT * 4 * CDIM;   // elements per key-quarter

    #pragma unroll
    for (int r = 0; r < 2; ++r) {   // stage merged ao tile (16 rows)
        int flat = r * 128 + t;
        int row = flat >> 4, c16 = (flat & 15) * 8;
        const int bn = b * NTOT + n0 + row;
        float m0 = Ms[bn], m1 = Ms[bn + 16384], m2 = Ms[bn + 32768], m3 = Ms[bn + 49152];
        float M = fmaxf(fmaxf(m0, m1), fmaxf(m2, m3));
        float w0 = Ls[bn]         * __expf(m0 - M);
        float w1 = Ls[bn + 16384] * __expf(m1 - M);
        float w2 = Ls[bn + 32768] * __expf(m2 - M);
        float w3 = Ls[bn + 49152] * __expf(m3 - M);
        const float inv = 1.0f / (w0 + w1 + w2 + w3);
        w0 *= inv; w1 *= inv; w2 *= inv; w3 *= inv;

        const size_t base = (size_t)bn * CDIM + c16;
        uint4 a0 = *(const uint4*)&Op[base];
        uint4 a1 = *(const uint4*)&Op[PER + base];
        uint4 a2 = *(const uint4*)&Op[2 * PER + base];
        uint4 a3 = *(const uint4*)&Op[3 * PER + base];
        const unsigned short* p0 = (const unsigned short*)&a0;
        const unsigned short* p1 = (const unsigned short*)&a1;
        const unsigned short* p2 = (const unsigned short*)&a2;
        const unsigned short* p3 = (const unsigned short*)&a3;
        unsigned short mv[8];
        #pragma unroll
        for (int j = 0; j < 8; ++j)
            mv[j] = f2h(w0 * h2f(p0[j]) + w1 * h2f(p1[j]) +
                        w2 * h2f(p2[j]) + w3 * h2f(p3[j]));
        *(uint4*)&As[row][c16] = *(const uint4*)mv;
    }
    __syncthreads();

    f16x8 bA[4];
    #pragma unroll
    for (int f = 0; f < 4; ++f)
        bA[f] = *(const f16x8*)&As[l15][f * 32 + quad * 8];

    #pragma unroll
    for (int ot = 0; ot < 4; ++ot) {
        const int o = w * 64 + ot * 16;
        floatx4 acc = (floatx4){0.f, 0.f, 0.f, 0.f};
        #pragma unroll
        for (int f = 0; f < 4; ++f) {
            f16x8 aW = *(const f16x8*)
                &Woh[(size_t)(o + l15) * CDIM + f * 32 + quad * 8];
            acc = mfma16(aW, bA[f], acc);
        }
        const int ob = o + quad * 4;
        #pragma unroll
        for (int r = 0; r < 4; ++r) {
            size_t idx = ((size_t)b * CDIM + ob + r) * NTOT + n0 + l15;
            out[idx] = acc[r] + bo[ob + r] + x[idx];
        }
    }
}

// ---------------------------------------------------------------------------
extern "C" void kernel_launch(void* const* d_in, const int* in_sizes, int n_in,
                              void* d_out, int out_size, void* d_ws, size_t ws_size,
                              hipStream_t stream)
{
    const float* x  = (const float*)d_in[0];
    const float* Wq = (const float*)d_in[1];
    const float* bq = (const float*)d_in[2];
    const float* Wk = (const float*)d_in[3];
    const float* bk = (const float*)d_in[4];
    const float* Wv = (const float*)d_in[5];
    const float* bv = (const float*)d_in[6];
    const float* Wo = (const float*)d_in[7];
    const float* bo = (const float*)d_in[8];
    float* out = (float*)d_out;

    const size_t PER = (size_t)4 * CDIM * NTOT;   // 2,097,152 elements
    unsigned short* q_ws  = (unsigned short*)d_ws;
    unsigned short* k_ws  = q_ws + PER;
    unsigned short* v_ws  = k_ws + PER;
    unsigned short* op_ws = v_ws + PER;           // fp16 [4][b][n][c] partials
    float*          ms_ws = (float*)(op_ws + 4 * PER);   // [4][b*n]
    float*          ls_ws = ms_ws + 4 * 16384;
    unsigned short* wh_ws = (unsigned short*)(ls_ws + 4 * 16384);  // [4][16384] fp16

    wcvt_kernel<<<dim3(16, 4), dim3(256), 0, stream>>>(Wq, Wk, Wv, Wo, wh_ws);
    qkv_proj_kernel<<<dim3(1024), dim3(128), 0, stream>>>(
        x, wh_ws, bq, bk, bv, q_ws, k_ws, v_ws);
    attn_kernel<<<dim3(512), dim3(256), 0, stream>>>(
        q_ws, k_ws, v_ws, op_ws, ms_ws, ls_ws);
    out_proj_kernel<<<dim3(1024), dim3(128), 0, stream>>>(
        op_ws, ms_ws, ls_ws, wh_ws + 3 * 16384, bo, x, out);
}